// Round 12
// baseline (534.272 us; speedup 1.0000x reference)
//
#include <hip/hip_runtime.h>
#include <math.h>

#define NB 32
#define NL 4096
#define ND 1024
#define NK 64
#define NSPLIT 16

typedef __bf16 bf16_t;
typedef __bf16 bf16x8 __attribute__((ext_vector_type(8)));
typedef __bf16 bf16x4 __attribute__((ext_vector_type(4)));
typedef float f32x4_t __attribute__((ext_vector_type(4)));

__device__ __forceinline__ unsigned short bfbits(float x) {
    bf16_t h = (bf16_t)x;
    return __builtin_bit_cast(unsigned short, h);
}

// ---------------- Kernel 0: W fp32 -> bf16
__global__ __launch_bounds__(256) void k_convw(const float* __restrict__ W,
                                               bf16_t* __restrict__ Wb) {
    const int i = (blockIdx.x * 256 + threadIdx.x) * 4;
    const float4 v = *(const float4*)(W + i);
    bf16x4 o;
    o[0] = (bf16_t)v.x; o[1] = (bf16_t)v.y; o[2] = (bf16_t)v.z; o[3] = (bf16_t)v.w;
    *(bf16x4*)(Wb + i) = o;
}

// ---------------- Fused: logits + online softmax + aggregation (feats read ONCE)
// Block = (b, split). Per 64-l chunk:
//   S: stage feats -> fT[1024 d][64 l] bf16 (XOR-swz)
//   L: logits MFMA (A: feats global, L2-hot; B: Wb) -> lgT[64 k][64 l] f32 (XOR-swz) + chunk max
//   stats: m_new/rescale/s_run online update
//   AGG: A = exp(lgT - m_new) hi/lo in regs, B = fT, acc (rescaled) += MFMA
// Epilogue: pO[b][sp][k][d] fp32 + (m,s) stats.
__global__ __launch_bounds__(512, 2) void k_fused(const float* __restrict__ feats,
                                                  const bf16_t* __restrict__ Wb,
                                                  const float* __restrict__ bias,
                                                  const int* __restrict__ lens,
                                                  float* __restrict__ pO,
                                                  float* __restrict__ mS,
                                                  float* __restrict__ sS) {
    const int bid = blockIdx.x;
    const int b  = bid >> 4;
    const int sp = bid & 15;
    const int t = threadIdx.x;
    const int w = t >> 6;
    const int lane = t & 63;
    const int lr = lane & 15;
    const int oct = lane >> 4;
    const int len = lens[b];
    const int nT = (len + 63) >> 6;
    const int t0 = (nT * sp) >> 4;
    const int t1 = (nT * (sp + 1)) >> 4;

    extern __shared__ char lds[];
    char*  const fT   = lds;                     // 131072 B
    char*  const lgT  = lds + 131072;            // 16384 B
    float* const red  = (float*)(lds + 147456);  // [64][17]
    float* const mrun = (float*)(lds + 151808);  // [64]
    float* const srun = (float*)(lds + 152064);  // [64]
    float* const mnew = (float*)(lds + 152320);  // [64]
    float* const rA   = (float*)(lds + 152576);  // [64]

    // role constants
    const int mtg = w >> 2, jq = w & 3;          // logits: 2 m-tiles, k-tile jq
    const int kh  = w & 1,  dh = w >> 1;         // agg: k-half, d-quarter
    const int dgrp = (t & 127) * 8;              // stage: 8 d cols
    const int lgq  = t >> 7;                     // stage: l quarter

    const int kA = jq * 16 + lr;                 // logits output k
    const float bs = bias[kA];
    const int kk0 = kh * 32 + lr;                // agg A k base (mt=0)

    if (t < 64) { mrun[t] = -1e30f; srun[t] = 0.f; }

    f32x4_t acc[2][16];
#pragma unroll
    for (int mi = 0; mi < 2; ++mi)
#pragma unroll
        for (int nt = 0; nt < 16; ++nt) acc[mi][nt] = (f32x4_t){0.f, 0.f, 0.f, 0.f};

    for (int tile = t0; tile < t1; ++tile) {
        const int l0 = tile * 64;
        __syncthreads();  // bar0: fT/lgT/red reusable

        // ---- STAGE fT (bf16, [d][l], swz c^=(d^(d>>3))&7)
#pragma unroll
        for (int half = 0; half < 2; ++half) {
            const int lbase = lgq * 16 + half * 8;
            unsigned cu[8][4];
#pragma unroll
            for (int lw = 0; lw < 4; ++lw) {
                const float* r0 = feats + ((size_t)b * NL + l0 + lbase + lw * 2) * ND + dgrp;
                const float* r1 = r0 + ND;
                const float4 a0 = *(const float4*)r0;
                const float4 a1 = *(const float4*)(r0 + 4);
                const float4 b0 = *(const float4*)r1;
                const float4 b1 = *(const float4*)(r1 + 4);
                cu[0][lw] = bfbits(a0.x) | ((unsigned)bfbits(b0.x) << 16);
                cu[1][lw] = bfbits(a0.y) | ((unsigned)bfbits(b0.y) << 16);
                cu[2][lw] = bfbits(a0.z) | ((unsigned)bfbits(b0.z) << 16);
                cu[3][lw] = bfbits(a0.w) | ((unsigned)bfbits(b0.w) << 16);
                cu[4][lw] = bfbits(a1.x) | ((unsigned)bfbits(b1.x) << 16);
                cu[5][lw] = bfbits(a1.y) | ((unsigned)bfbits(b1.y) << 16);
                cu[6][lw] = bfbits(a1.z) | ((unsigned)bfbits(b1.z) << 16);
                cu[7][lw] = bfbits(a1.w) | ((unsigned)bfbits(b1.w) << 16);
            }
#pragma unroll
            for (int j = 0; j < 8; ++j) {
                const int d = dgrp + j;
                const int c = (lbase >> 3) ^ ((d ^ (d >> 3)) & 7);
                *(uint4*)(fT + d * 128 + c * 16) =
                    make_uint4(cu[j][0], cu[j][1], cu[j][2], cu[j][3]);
            }
        }

        // ---- LOGITS (verified conv: A m=lr/c=oct*8+j; B n=lr; C col=lr, row=oct*4+r)
        float vals[2][4];
        {
            const float* fp0 = feats + ((size_t)b * NL + l0 + (mtg * 2 + 0) * 16 + lr) * ND + oct * 8;
            const float* fp1 = feats + ((size_t)b * NL + l0 + (mtg * 2 + 1) * 16 + lr) * ND + oct * 8;
            const bf16_t* wr = Wb + (size_t)kA * ND + oct * 8;
            f32x4_t la0 = (f32x4_t){0.f, 0.f, 0.f, 0.f};
            f32x4_t la1 = (f32x4_t){0.f, 0.f, 0.f, 0.f};
#pragma unroll 2
            for (int kk = 0; kk < 32; ++kk) {
                const int d = kk * 32;
                const float4 a0 = *(const float4*)(fp0 + d);
                const float4 a1 = *(const float4*)(fp0 + d + 4);
                const float4 c0 = *(const float4*)(fp1 + d);
                const float4 c1 = *(const float4*)(fp1 + d + 4);
                bf16x8 af0, af1;
                af0[0] = (bf16_t)a0.x; af0[1] = (bf16_t)a0.y; af0[2] = (bf16_t)a0.z; af0[3] = (bf16_t)a0.w;
                af0[4] = (bf16_t)a1.x; af0[5] = (bf16_t)a1.y; af0[6] = (bf16_t)a1.z; af0[7] = (bf16_t)a1.w;
                af1[0] = (bf16_t)c0.x; af1[1] = (bf16_t)c0.y; af1[2] = (bf16_t)c0.z; af1[3] = (bf16_t)c0.w;
                af1[4] = (bf16_t)c1.x; af1[5] = (bf16_t)c1.y; af1[6] = (bf16_t)c1.z; af1[7] = (bf16_t)c1.w;
                const bf16x8 bf = *(const bf16x8*)(wr + d);
                la0 = __builtin_amdgcn_mfma_f32_16x16x32_bf16(af0, bf, la0, 0, 0, 0);
                la1 = __builtin_amdgcn_mfma_f32_16x16x32_bf16(af1, bf, la1, 0, 0, 0);
            }
#pragma unroll
            for (int r = 0; r < 4; ++r) { vals[0][r] = la0[r] + bs; vals[1][r] = la1[r] + bs; }
        }
#pragma unroll
        for (int mi = 0; mi < 2; ++mi) {
            const int mt = mtg * 2 + mi;
            const int c = (mt * 4 + oct) ^ (kA & 15);
            *(float4*)(lgT + kA * 256 + c * 16) =
                make_float4(vals[mi][0], vals[mi][1], vals[mi][2], vals[mi][3]);
            const int lb = l0 + mt * 16 + oct * 4;
            float vm = -1e30f;
#pragma unroll
            for (int r = 0; r < 4; ++r)
                if (lb + r < len) vm = fmaxf(vm, vals[mi][r]);
            red[kA * 17 + mt * 4 + oct] = vm;
        }
        __syncthreads();  // bar1: lgT + red-max ready

        if (t < 64) {
            float mc = red[t * 17];
#pragma unroll
            for (int q = 1; q < 16; ++q) mc = fmaxf(mc, red[t * 17 + q]);
            const float mo = mrun[t];
            const float mn_ = fmaxf(mo, mc);
            mnew[t] = mn_;
            rA[t] = __expf(mo - mn_);
            mrun[t] = mn_;
        }
        __syncthreads();  // bar2: mnew/rA ready

        {
            const float mk = mnew[kA];
#pragma unroll
            for (int mi = 0; mi < 2; ++mi) {
                const int mt = mtg * 2 + mi;
                const int lb = l0 + mt * 16 + oct * 4;
                float sj = 0.f;
#pragma unroll
                for (int r = 0; r < 4; ++r)
                    if (lb + r < len) sj += __expf(vals[mi][r] - mk);
                red[kA * 17 + mt * 4 + oct] = sj;
            }
        }
        __syncthreads();  // bar3: red-s ready

        if (t < 64) {
            float sc_ = 0.f;
#pragma unroll
            for (int q = 0; q < 16; ++q) sc_ += red[t * 17 + q];
            srun[t] = srun[t] * rA[t] + sc_;
        }

        // ---- rescale acc to new basis
        {
            const float4 ra0 = *(const float4*)&rA[kh * 32 + oct * 4];
            const float4 ra1 = *(const float4*)&rA[kh * 32 + 16 + oct * 4];
#pragma unroll
            for (int nt = 0; nt < 16; ++nt) {
                acc[0][nt][0] *= ra0.x; acc[0][nt][1] *= ra0.y;
                acc[0][nt][2] *= ra0.z; acc[0][nt][3] *= ra0.w;
                acc[1][nt][0] *= ra1.x; acc[1][nt][1] *= ra1.y;
                acc[1][nt][2] *= ra1.z; acc[1][nt][3] *= ra1.w;
            }
        }

        // ---- A-frags: p = exp(logit - m_new), hi/lo exact split
        bf16x8 afH[2][2], afL[2][2];
#pragma unroll
        for (int mi = 0; mi < 2; ++mi) {
            const int kkm = kk0 + mi * 16;
            const float mk = mnew[kkm];
#pragma unroll
            for (int ks = 0; ks < 2; ++ks) {
                const int c0 = (ks * 8 + oct * 2) ^ lr;       // (kkm&15)==lr
                const int c1 = (ks * 8 + oct * 2 + 1) ^ lr;
                const float4 g0 = *(const float4*)(lgT + kkm * 256 + c0 * 16);
                const float4 g1 = *(const float4*)(lgT + kkm * 256 + c1 * 16);
                const int lb = l0 + ks * 32 + oct * 8;
                float e0 = (lb + 0 < len) ? __expf(g0.x - mk) : 0.f;
                float e1 = (lb + 1 < len) ? __expf(g0.y - mk) : 0.f;
                float e2 = (lb + 2 < len) ? __expf(g0.z - mk) : 0.f;
                float e3 = (lb + 3 < len) ? __expf(g0.w - mk) : 0.f;
                float e4 = (lb + 4 < len) ? __expf(g1.x - mk) : 0.f;
                float e5 = (lb + 5 < len) ? __expf(g1.y - mk) : 0.f;
                float e6 = (lb + 6 < len) ? __expf(g1.z - mk) : 0.f;
                float e7 = (lb + 7 < len) ? __expf(g1.w - mk) : 0.f;
                bf16x8 h, l2;
                h[0] = (bf16_t)e0; l2[0] = (bf16_t)(e0 - (float)h[0]);
                h[1] = (bf16_t)e1; l2[1] = (bf16_t)(e1 - (float)h[1]);
                h[2] = (bf16_t)e2; l2[2] = (bf16_t)(e2 - (float)h[2]);
                h[3] = (bf16_t)e3; l2[3] = (bf16_t)(e3 - (float)h[3]);
                h[4] = (bf16_t)e4; l2[4] = (bf16_t)(e4 - (float)h[4]);
                h[5] = (bf16_t)e5; l2[5] = (bf16_t)(e5 - (float)h[5]);
                h[6] = (bf16_t)e6; l2[6] = (bf16_t)(e6 - (float)h[6]);
                h[7] = (bf16_t)e7; l2[7] = (bf16_t)(e7 - (float)h[7]);
                afH[mi][ks] = h; afL[mi][ks] = l2;
            }
        }

        // ---- AGG MFMA: B from fT, reuse each B across 4 MFMAs
#pragma unroll
        for (int ks = 0; ks < 2; ++ks) {
#pragma unroll
            for (int nt = 0; nt < 16; ++nt) {
                const int d = dh * 256 + nt * 16 + lr;
                const int c = (ks * 4 + oct) ^ ((d ^ (d >> 3)) & 7);
                const bf16x8 bv = *(const bf16x8*)(fT + d * 128 + c * 16);
                acc[0][nt] = __builtin_amdgcn_mfma_f32_16x16x32_bf16(afH[0][ks], bv, acc[0][nt], 0, 0, 0);
                acc[0][nt] = __builtin_amdgcn_mfma_f32_16x16x32_bf16(afL[0][ks], bv, acc[0][nt], 0, 0, 0);
                acc[1][nt] = __builtin_amdgcn_mfma_f32_16x16x32_bf16(afH[1][ks], bv, acc[1][nt], 0, 0, 0);
                acc[1][nt] = __builtin_amdgcn_mfma_f32_16x16x32_bf16(afL[1][ks], bv, acc[1][nt], 0, 0, 0);
            }
        }
    }

    // ---- epilogue: unnormalized partials + stats
    float* po = pO + (size_t)(b * NSPLIT + sp) * NK * ND;
#pragma unroll
    for (int mi = 0; mi < 2; ++mi)
#pragma unroll
        for (int nt = 0; nt < 16; ++nt) {
            const int d = dh * 256 + nt * 16 + lr;
#pragma unroll
            for (int r = 0; r < 4; ++r) {
                const int k = kh * 32 + mi * 16 + oct * 4 + r;
                po[(size_t)k * ND + d] = acc[mi][nt][r];
            }
        }
    if (t < 64) {
        mS[(size_t)(b * NSPLIT + sp) * 64 + t] = mrun[t];
        sS[(size_t)(b * NSPLIT + sp) * 64 + t] = srun[t];
    }
}

// ---------------- global stats -> per-split scale = exp(m_s - M) / S
__global__ void k_gstats(const float* __restrict__ mS, const float* __restrict__ sS,
                         float* __restrict__ scale) {
    const int b = blockIdx.x;
    const int k = threadIdx.x;  // 64
    float M = -1e30f;
#pragma unroll
    for (int s = 0; s < NSPLIT; ++s) M = fmaxf(M, mS[(b * NSPLIT + s) * 64 + k]);
    float S = 0.f;
#pragma unroll
    for (int s = 0; s < NSPLIT; ++s)
        S += sS[(b * NSPLIT + s) * 64 + k] * __expf(mS[(b * NSPLIT + s) * 64 + k] - M);
    const float inv = 1.f / S;
#pragma unroll
    for (int s = 0; s < NSPLIT; ++s)
        scale[(b * NSPLIT + s) * 64 + k] = __expf(mS[(b * NSPLIT + s) * 64 + k] - M) * inv;
}

// ---------------- combine: scaled partial sum, subtract centroid, min over k
__global__ __launch_bounds__(128) void k_combine(const float* __restrict__ pO,
                                                 const float* __restrict__ scale,
                                                 const float* __restrict__ centroids,
                                                 float* __restrict__ outun) {
    const int b = blockIdx.x >> 3;
    const int d = (blockIdx.x & 7) * 128 + threadIdx.x;  // 0..1023
    __shared__ float sc[NSPLIT][64];
    for (int i = threadIdx.x; i < NSPLIT * 64; i += 128)
        sc[i >> 6][i & 63] = scale[b * NSPLIT * 64 + i];
    __syncthreads();
    const float* pb = pO + (size_t)b * NSPLIT * NK * ND;
    float mn = 1e30f;
    for (int k = 0; k < NK; ++k) {
        float v = 0.f;
#pragma unroll
        for (int s = 0; s < NSPLIT; ++s)
            v += pb[(size_t)(s * NK + k) * ND + d] * sc[s][k];
        v -= centroids[(size_t)k * ND + d];
        mn = fminf(mn, v);
    }
    outun[(size_t)b * ND + d] = mn;
}

// ---------------- L2-normalize rows
__global__ __launch_bounds__(256) void k_norm(const float* __restrict__ outun,
                                              float* __restrict__ out) {
    const int b = blockIdx.x;
    const int t = threadIdx.x;
    float ss = 0.f;
    for (int d = t; d < ND; d += 256) {
        const float v = outun[(size_t)b * ND + d];
        ss += v * v;
    }
#pragma unroll
    for (int off = 32; off > 0; off >>= 1) ss += __shfl_down(ss, off);
    __shared__ float red[4];
    if ((t & 63) == 0) red[t >> 6] = ss;
    __syncthreads();
    const float tot = red[0] + red[1] + red[2] + red[3];
    const float inv = 1.0f / fmaxf(sqrtf(tot), 1e-12f);
    for (int d = t; d < ND; d += 256) out[(size_t)b * ND + d] = outun[(size_t)b * ND + d] * inv;
}

extern "C" void kernel_launch(void* const* d_in, const int* in_sizes, int n_in,
                              void* d_out, int out_size, void* d_ws, size_t ws_size,
                              hipStream_t stream) {
    const float* feats     = (const float*)d_in[0];
    const int*   lens      = (const int*)d_in[1];
    const float* W         = (const float*)d_in[2];
    const float* bias      = (const float*)d_in[3];
    const float* centroids = (const float*)d_in[4];
    float* out = (float*)d_out;

    char* ws = (char*)d_ws;
    size_t off = 0;
    bf16_t* Wb   = (bf16_t*)(ws + off); off += (size_t)NK * ND * sizeof(bf16_t);
    float* pO    = (float*)(ws + off);  off += (size_t)NB * NSPLIT * NK * ND * sizeof(float); // 134 MB
    float* mS    = (float*)(ws + off);  off += (size_t)NB * NSPLIT * 64 * sizeof(float);
    float* sS    = (float*)(ws + off);  off += (size_t)NB * NSPLIT * 64 * sizeof(float);
    float* scale = (float*)(ws + off);  off += (size_t)NB * NSPLIT * 64 * sizeof(float);
    float* outun = (float*)(ws + off);  off += (size_t)NB * ND * sizeof(float);

    const size_t LDSB = 152832;  // fT 128K + lgT 16K + red/stats

    k_convw<<<NK * ND / 1024, 256, 0, stream>>>(W, Wb);
    k_fused<<<NB * NSPLIT, 512, LDSB, stream>>>(feats, Wb, bias, lens, pO, mS, sS);
    k_gstats<<<NB, 64, 0, stream>>>(mS, sS, scale);
    k_combine<<<NB * 8, 128, 0, stream>>>(pO, scale, centroids, outun);
    k_norm<<<NB, 256, 0, stream>>>(outun, out);
}